// Round 1
// baseline (12521.734 us; speedup 1.0000x reference)
//
#include <hip/hip_runtime.h>
#include <math.h>

#define S_DIM 512
#define B_DIM 512
#define E_DIM 768

// ---------------------------------------------------------------------------
// GEMM NN: C[M,N] = A[M,K] @ B[K,N], fp32, row-major.
// BM=BN=128, BK=16, 256 threads (16x16), 8x8 micro-tile (two 4-wide groups).
// A-tile stored transposed in LDS ([kk][r]) so inner-loop reads are broadcast.
// Batched over blockIdx.z via element strides.
// ---------------------------------------------------------------------------
__global__ __launch_bounds__(256) void gemm_nn_f32(
    const float* __restrict__ A, const float* __restrict__ B, float* __restrict__ C,
    int M, int N, int K, long aStrideZ, long bStrideZ, long cStrideZ)
{
  A += (long)blockIdx.z * aStrideZ;
  B += (long)blockIdx.z * bStrideZ;
  C += (long)blockIdx.z * cStrideZ;

  __shared__ float As[16][128];  // [kk][r]
  __shared__ float Bs[16][128];  // [kk][c]

  const int tid = threadIdx.x;
  const int tx = tid & 15;
  const int ty = tid >> 4;
  const int m0 = blockIdx.y * 128;
  const int n0 = blockIdx.x * 128;

  float acc[8][8];
  #pragma unroll
  for (int i = 0; i < 8; ++i)
    #pragma unroll
    for (int j = 0; j < 8; ++j) acc[i][j] = 0.0f;

  for (int k0 = 0; k0 < K; k0 += 16) {
    // stage A-tile (128 rows x 16 k) transposed: 512 float4 loads, 2/thread
    #pragma unroll
    for (int rep = 0; rep < 2; ++rep) {
      int e = tid + rep * 256;
      int r = e >> 2, kq = (e & 3) << 2;
      float4 v = *(const float4*)(A + (long)(m0 + r) * K + k0 + kq);
      As[kq + 0][r] = v.x; As[kq + 1][r] = v.y;
      As[kq + 2][r] = v.z; As[kq + 3][r] = v.w;
    }
    // stage B-tile (16 k x 128 n): 512 float4 loads, 2/thread
    #pragma unroll
    for (int rep = 0; rep < 2; ++rep) {
      int e = tid + rep * 256;
      int kk = e >> 5, c = (e & 31) << 2;
      *(float4*)&Bs[kk][c] = *(const float4*)(B + (long)(k0 + kk) * N + n0 + c);
    }
    __syncthreads();
    #pragma unroll
    for (int kk = 0; kk < 16; ++kk) {
      float a[8], b[8];
      *(float4*)&a[0] = *(const float4*)&As[kk][ty * 4];
      *(float4*)&a[4] = *(const float4*)&As[kk][64 + ty * 4];
      *(float4*)&b[0] = *(const float4*)&Bs[kk][tx * 4];
      *(float4*)&b[4] = *(const float4*)&Bs[kk][64 + tx * 4];
      #pragma unroll
      for (int i = 0; i < 8; ++i)
        #pragma unroll
        for (int j = 0; j < 8; ++j)
          acc[i][j] = fmaf(a[i], b[j], acc[i][j]);
    }
    __syncthreads();
  }

  #pragma unroll
  for (int i = 0; i < 8; ++i) {
    int r = m0 + ((i < 4) ? (ty * 4 + i) : (64 + ty * 4 + (i - 4)));
    float* crow = C + (long)r * N + n0;
    *(float4*)(crow + tx * 4)      = *(float4*)&acc[i][0];
    *(float4*)(crow + 64 + tx * 4) = *(float4*)&acc[i][4];
  }
}

// ---------------------------------------------------------------------------
// score_softmax: per s, P = softmax(Q K^T / sqrt(E)) rows in [r0, r0+32).
// 256 threads = 8 (ty, row groups of 4) x 32 (tx); micro 4 rows x 16 cols.
// Logits live entirely in registers; row softmax via __shfl_xor within the
// 32-lane half-wave that owns the row.
// ---------------------------------------------------------------------------
__global__ __launch_bounds__(256) void score_softmax(
    const float* __restrict__ Q, const float* __restrict__ Kmat, float* __restrict__ P)
{
  const int s = blockIdx.y;
  const float* Qs = Q + (long)s * B_DIM * E_DIM;
  const float* Ks = Kmat + (long)s * B_DIM * E_DIM;
  float* Ps = P + (long)s * B_DIM * B_DIM;

  __shared__ float Qt[16][32];    // [kk][r]   2 KB
  __shared__ float Kt[16][512];   // [kk][j]  32 KB

  const int tid = threadIdx.x;
  const int tx = tid & 31;
  const int ty = tid >> 5;
  const int r0 = blockIdx.x * 32;

  float acc[4][16];
  #pragma unroll
  for (int i = 0; i < 4; ++i)
    #pragma unroll
    for (int j = 0; j < 16; ++j) acc[i][j] = 0.0f;

  for (int k0 = 0; k0 < E_DIM; k0 += 16) {
    if (tid < 128) {
      int r = tid >> 2, kq = (tid & 3) << 2;
      float4 v = *(const float4*)(Qs + (long)(r0 + r) * E_DIM + k0 + kq);
      Qt[kq + 0][r] = v.x; Qt[kq + 1][r] = v.y;
      Qt[kq + 2][r] = v.z; Qt[kq + 3][r] = v.w;
    }
    #pragma unroll
    for (int rep = 0; rep < 8; ++rep) {
      int e = tid + rep * 256;
      int j = e >> 2, kq = (e & 3) << 2;
      float4 v = *(const float4*)(Ks + (long)j * E_DIM + k0 + kq);
      Kt[kq + 0][j] = v.x; Kt[kq + 1][j] = v.y;
      Kt[kq + 2][j] = v.z; Kt[kq + 3][j] = v.w;
    }
    __syncthreads();
    #pragma unroll
    for (int kk = 0; kk < 16; ++kk) {
      float a[4], b[16];
      *(float4*)&a[0] = *(const float4*)&Qt[kk][ty * 4];
      #pragma unroll
      for (int jj = 0; jj < 8; ++jj)
        *(float2*)&b[jj * 2] = *(const float2*)&Kt[kk][tx * 2 + jj * 64];
      #pragma unroll
      for (int i = 0; i < 4; ++i)
        #pragma unroll
        for (int j = 0; j < 16; ++j)
          acc[i][j] = fmaf(a[i], b[j], acc[i][j]);
    }
    __syncthreads();
  }

  const float scale = 0.03608439182435161f;  // 1/sqrt(768)
  #pragma unroll
  for (int i = 0; i < 4; ++i) {
    float m = -3.0e38f;
    #pragma unroll
    for (int j = 0; j < 16; ++j) { acc[i][j] *= scale; m = fmaxf(m, acc[i][j]); }
    #pragma unroll
    for (int off = 16; off >= 1; off >>= 1) m = fmaxf(m, __shfl_xor(m, off, 64));
    float sum = 0.0f;
    #pragma unroll
    for (int j = 0; j < 16; ++j) { acc[i][j] = __expf(acc[i][j] - m); sum += acc[i][j]; }
    #pragma unroll
    for (int off = 16; off >= 1; off >>= 1) sum += __shfl_xor(sum, off, 64);
    float inv = 1.0f / sum;
    #pragma unroll
    for (int j = 0; j < 16; ++j) acc[i][j] *= inv;
  }

  #pragma unroll
  for (int i = 0; i < 4; ++i) {
    float* prow = Ps + (long)(r0 + ty * 4 + i) * B_DIM;
    #pragma unroll
    for (int jj = 0; jj < 8; ++jj)
      *(float2*)&prow[tx * 2 + jj * 64] = *(float2*)&acc[i][jj * 2];
  }
}

// ---------------------------------------------------------------------------
extern "C" void kernel_launch(void* const* d_in, const int* in_sizes, int n_in,
                              void* d_out, int out_size, void* d_ws, size_t ws_size,
                              hipStream_t stream) {
  const float* inputs = (const float*)d_in[0];
  const float* rot    = (const float*)d_in[1];
  const float* ent    = (const float*)d_in[2];
  float* out = (float*)d_out;
  float* ws  = (float*)d_ws;

  const long perS_QK = (long)B_DIM * E_DIM;  // 393216 floats per s for Q or K
  const long perS_P  = (long)B_DIM * B_DIM;  // 262144 floats per s for P
  const long perS_bytes = (2 * perS_QK + perS_P) * 4;  // 4 MiB per s

  int SC = (int)(ws_size / perS_bytes);
  if (SC < 1) SC = 1;
  if (SC > S_DIM) SC = S_DIM;

  float* Qw = ws;
  float* Kw = ws + (long)SC * perS_QK;
  float* Pw = ws + 2 * (long)SC * perS_QK;

  for (int s0 = 0; s0 < S_DIM; s0 += SC) {
    int cur = (S_DIM - s0 < SC) ? (S_DIM - s0) : SC;
    const float* Ain = inputs + (long)s0 * B_DIM * E_DIM;

    // Q = X @ R, K = X @ W   (M = cur*512, N = 768, K = 768)
    dim3 g1(E_DIM / 128, cur * (B_DIM / 128), 1);
    gemm_nn_f32<<<g1, 256, 0, stream>>>(Ain, rot, Qw, cur * B_DIM, E_DIM, E_DIM, 0, 0, 0);
    gemm_nn_f32<<<g1, 256, 0, stream>>>(Ain, ent, Kw, cur * B_DIM, E_DIM, E_DIM, 0, 0, 0);

    // P = softmax(Q K^T / sqrt(E)) per s
    dim3 g2(B_DIM / 32, cur, 1);
    score_softmax<<<g2, 256, 0, stream>>>(Qw, Kw, Pw);

    // out = P @ V  (per s: 512x768 = (512x512)@(512x768))
    dim3 g3(E_DIM / 128, B_DIM / 128, cur);
    gemm_nn_f32<<<g3, 256, 0, stream>>>(Pw, Ain, out + (long)s0 * B_DIM * E_DIM,
                                        B_DIM, E_DIM, B_DIM,
                                        perS_P, perS_QK, perS_QK);
  }
}

// Round 2
// 3167.207 us; speedup vs baseline: 3.9536x; 3.9536x over previous
//
#include <hip/hip_runtime.h>
#include <math.h>

typedef unsigned short ushort_t;
typedef __attribute__((ext_vector_type(8))) short bf16x8;   // 8 bf16 bit-patterns (4 VGPRs)
typedef __attribute__((ext_vector_type(4))) float f32x4;

#define SD 512
#define BD 512
#define ED 768
#define SCALE 0.03608439182435161f  // 1/sqrt(768)

__device__ __forceinline__ ushort_t f2bf(float f) {
  unsigned u = __float_as_uint(f);
  return (ushort_t)((u + 0x7FFFu + ((u >> 16) & 1u)) >> 16);  // RNE
}
__device__ __forceinline__ float bf2f(ushort_t h) {
  return __uint_as_float(((unsigned)h) << 16);
}

// ---------------------------------------------------------------------------
// Generic 128x128xK MFMA GEMM, "NT" form: both operands staged as rows[idx][k]
// (A rows = output rows, B rows = output cols), k-contiguous in global memory.
// BK=32, 4 waves (2x2), each wave 64x64 = 4x4 fragments of 16x16x32 bf16 MFMA.
// LDS XOR-swizzle: slot' = slot ^ ((row>>1)&3)  -> 2-way conflicts only (free).
// AM/BM: 0 = fp32 source, split into hi+lo bf16 planes during staging
//        1 = pre-split bf16 hi/lo planes (copy staging)
//        2 = single bf16 plane
// EPI:   0 = fp32 store (scaled), 1 = split hi/lo bf16 store (zMode: Z layout)
// TRIPLE: bf16x3 product (hi*hi + hi*lo + lo*hi)
// ---------------------------------------------------------------------------
struct MMP {
  const float* Af;
  const ushort_t* Ahi; const ushort_t* Alo;
  long aLd, aZ;
  const float* Bf;
  const ushort_t* Bhi; const ushort_t* Blo;
  long bLd, bZ;
  float* Cf; float cScale;
  ushort_t* Chi; ushort_t* Clo;
  long cLd, cZ;
  int zMode;
  int K;
};

template <int AM, int BM, int EPI, bool TRIPLE>
__global__ __launch_bounds__(256) void mm(MMP P)
{
  __shared__ ushort_t lds[16384];   // Ah|Al|Bh|Bl, 4096 each (32 KB)
  ushort_t* Ah = lds;
  ushort_t* Al = lds + 4096;
  ushort_t* Bh = lds + 8192;
  ushort_t* Bl = lds + 12288;

  const int tid = threadIdx.x;
  const int z = blockIdx.z;
  int bx = blockIdx.x, by = blockIdx.y;
  if (gridDim.z == 1) {                       // XCD-aware swizzle (bijective)
    int nwg = gridDim.x * gridDim.y;
    if ((nwg & 7) == 0) {
      int id = by * gridDim.x + bx;
      int q = nwg >> 3;
      int wid = (id & 7) * q + (id >> 3);
      bx = wid % gridDim.x;
      by = wid / gridDim.x;
    }
  }
  const int m0 = by * 128, n0 = bx * 128;

  const int lane = tid & 63;
  const int wave = tid >> 6;
  const int wm = (wave >> 1) * 64, wn = (wave & 1) * 64;
  const int lr = lane & 15, g = lane >> 4;

  f32x4 acc[4][4];
  #pragma unroll
  for (int i = 0; i < 4; ++i)
    #pragma unroll
    for (int j = 0; j < 4; ++j) {
      f32x4 zv = {0.f, 0.f, 0.f, 0.f};
      acc[i][j] = zv;
    }

  for (int k0 = 0; k0 < P.K; k0 += 32) {
    // ---------------- stage A ----------------
    if constexpr (AM == 0) {
      const float* A = P.Af + (long)z * P.aZ;
      #pragma unroll
      for (int rep = 0; rep < 4; ++rep) {
        int idx = tid + rep * 256;
        int row = idx >> 3, q = idx & 7;
        float4 v = *(const float4*)(A + (long)(m0 + row) * P.aLd + k0 + q * 4);
        int off = row * 32 + (((q >> 1) ^ ((row >> 1) & 3)) << 3) + ((q & 1) << 2);
        ushort_t hh[4], ll[4];
        hh[0] = f2bf(v.x); ll[0] = f2bf(v.x - bf2f(hh[0]));
        hh[1] = f2bf(v.y); ll[1] = f2bf(v.y - bf2f(hh[1]));
        hh[2] = f2bf(v.z); ll[2] = f2bf(v.z - bf2f(hh[2]));
        hh[3] = f2bf(v.w); ll[3] = f2bf(v.w - bf2f(hh[3]));
        *(uint2*)(Ah + off) = *(uint2*)hh;
        *(uint2*)(Al + off) = *(uint2*)ll;
      }
    } else {
      const ushort_t* As = P.Ahi + (long)z * P.aZ;
      #pragma unroll
      for (int rep = 0; rep < 2; ++rep) {
        int idx = tid + rep * 256;
        int row = idx >> 2, h8 = idx & 3;
        int off = row * 32 + ((h8 ^ ((row >> 1) & 3)) << 3);
        long gsrc = (long)(m0 + row) * P.aLd + k0 + h8 * 8;
        *(uint4*)(Ah + off) = *(const uint4*)(As + gsrc);
        if constexpr (AM == 1) {
          const ushort_t* Als = P.Alo + (long)z * P.aZ;
          *(uint4*)(Al + off) = *(const uint4*)(Als + gsrc);
        }
      }
    }
    // ---------------- stage B ----------------
    if constexpr (BM == 0) {
      const float* B = P.Bf + (long)z * P.bZ;
      #pragma unroll
      for (int rep = 0; rep < 4; ++rep) {
        int idx = tid + rep * 256;
        int row = idx >> 3, q = idx & 7;
        float4 v = *(const float4*)(B + (long)(n0 + row) * P.bLd + k0 + q * 4);
        int off = row * 32 + (((q >> 1) ^ ((row >> 1) & 3)) << 3) + ((q & 1) << 2);
        ushort_t hh[4], ll[4];
        hh[0] = f2bf(v.x); ll[0] = f2bf(v.x - bf2f(hh[0]));
        hh[1] = f2bf(v.y); ll[1] = f2bf(v.y - bf2f(hh[1]));
        hh[2] = f2bf(v.z); ll[2] = f2bf(v.z - bf2f(hh[2]));
        hh[3] = f2bf(v.w); ll[3] = f2bf(v.w - bf2f(hh[3]));
        *(uint2*)(Bh + off) = *(uint2*)hh;
        *(uint2*)(Bl + off) = *(uint2*)ll;
      }
    } else {
      const ushort_t* Bs = P.Bhi + (long)z * P.bZ;
      #pragma unroll
      for (int rep = 0; rep < 2; ++rep) {
        int idx = tid + rep * 256;
        int row = idx >> 2, h8 = idx & 3;
        int off = row * 32 + ((h8 ^ ((row >> 1) & 3)) << 3);
        long gsrc = (long)(n0 + row) * P.bLd + k0 + h8 * 8;
        *(uint4*)(Bh + off) = *(const uint4*)(Bs + gsrc);
        if constexpr (BM == 1) {
          const ushort_t* Bls = P.Blo + (long)z * P.bZ;
          *(uint4*)(Bl + off) = *(const uint4*)(Bls + gsrc);
        }
      }
    }
    __syncthreads();

    // ---------------- compute ----------------
    bf16x8 ar[4], br[4];
    #pragma unroll
    for (int i = 0; i < 4; ++i) {
      int row = wm + i * 16 + lr;
      ar[i] = *(const bf16x8*)(Ah + row * 32 + ((g ^ ((row >> 1) & 3)) << 3));
    }
    #pragma unroll
    for (int j = 0; j < 4; ++j) {
      int row = wn + j * 16 + lr;
      br[j] = *(const bf16x8*)(Bh + row * 32 + ((g ^ ((row >> 1) & 3)) << 3));
    }
    #pragma unroll
    for (int i = 0; i < 4; ++i)
      #pragma unroll
      for (int j = 0; j < 4; ++j)
        acc[i][j] = __builtin_amdgcn_mfma_f32_16x16x32_bf16(ar[i], br[j], acc[i][j], 0, 0, 0);

    if constexpr (TRIPLE) {
      #pragma unroll
      for (int j = 0; j < 4; ++j) {
        int row = wn + j * 16 + lr;
        bf16x8 blv = *(const bf16x8*)(Bl + row * 32 + ((g ^ ((row >> 1) & 3)) << 3));
        #pragma unroll
        for (int i = 0; i < 4; ++i)
          acc[i][j] = __builtin_amdgcn_mfma_f32_16x16x32_bf16(ar[i], blv, acc[i][j], 0, 0, 0);
      }
      #pragma unroll
      for (int i = 0; i < 4; ++i) {
        int row = wm + i * 16 + lr;
        bf16x8 alv = *(const bf16x8*)(Al + row * 32 + ((g ^ ((row >> 1) & 3)) << 3));
        #pragma unroll
        for (int j = 0; j < 4; ++j)
          acc[i][j] = __builtin_amdgcn_mfma_f32_16x16x32_bf16(alv, br[j], acc[i][j], 0, 0, 0);
      }
    }
    __syncthreads();
  }

  // ---------------- epilogue ----------------
  // C/D layout (m89-verified): col = lane&15, row = (lane>>4)*4 + reg
  #pragma unroll
  for (int i = 0; i < 4; ++i) {
    #pragma unroll
    for (int j = 0; j < 4; ++j) {
      int colG = n0 + wn + j * 16 + lr;
      #pragma unroll
      for (int r = 0; r < 4; ++r) {
        int rowG = m0 + wm + i * 16 + g * 4 + r;
        float v = acc[i][j][r];
        if constexpr (EPI == 0) {
          P.Cf[(long)z * P.cZ + (long)rowG * P.cLd + colG] = v * P.cScale;
        } else {
          ushort_t hi = f2bf(v);
          ushort_t lo = f2bf(v - bf2f(hi));
          long off;
          if (P.zMode) off = (long)(rowG >> 9) * 786432 + (long)(rowG & 511) * 768 + colG;
          else         off = (long)rowG * P.cLd + colG;
          P.Chi[off] = hi;
          P.Clo[off] = lo;
        }
      }
    }
  }
}

// ---------------------------------------------------------------------------
// Row softmax: scores (fp32, [z][512][512], pre-scaled) -> P bf16.
// One wave per row: 8 elems/lane, full-wave shfl reduce.
// ---------------------------------------------------------------------------
__global__ __launch_bounds__(256) void softmax_rows(const float* __restrict__ S,
                                                    ushort_t* __restrict__ Pm)
{
  const int z = blockIdx.y;
  const int row = blockIdx.x * 4 + (threadIdx.x >> 6);
  const int lane = threadIdx.x & 63;
  const float* Sr = S + (long)z * 262144 + (long)row * 512 + lane * 8;
  float x[8];
  *(float4*)&x[0] = *(const float4*)(Sr);
  *(float4*)&x[4] = *(const float4*)(Sr + 4);
  float m = x[0];
  #pragma unroll
  for (int i = 1; i < 8; ++i) m = fmaxf(m, x[i]);
  #pragma unroll
  for (int off = 32; off >= 1; off >>= 1) m = fmaxf(m, __shfl_xor(m, off, 64));
  float e[8], sum = 0.f;
  #pragma unroll
  for (int i = 0; i < 8; ++i) { e[i] = __expf(x[i] - m); sum += e[i]; }
  #pragma unroll
  for (int off = 32; off >= 1; off >>= 1) sum += __shfl_xor(sum, off, 64);
  float inv = 1.0f / sum;
  ushort_t h[8];
  #pragma unroll
  for (int i = 0; i < 8; ++i) h[i] = f2bf(e[i] * inv);
  *(uint4*)(Pm + (long)z * 262144 + (long)row * 512 + lane * 8) = *(uint4*)h;
}

// ---------------------------------------------------------------------------
// Per-s transpose + bf16 cast: X[s][b][e] fp32 -> Xt[si][e][b] bf16.
// ---------------------------------------------------------------------------
__global__ __launch_bounds__(256) void transpose_split(const float* __restrict__ X,
                                                       ushort_t* __restrict__ Xt, int s0)
{
  const int si = blockIdx.z;
  const long s = s0 + si;
  const int b0 = blockIdx.x * 64, e0 = blockIdx.y * 64;
  __shared__ float tile[64][65];
  const int t = threadIdx.x;
  const int bloc = t >> 4, eq = t & 15;
  #pragma unroll
  for (int r = 0; r < 4; ++r) {
    int b = bloc + r * 16;
    float4 v = *(const float4*)(X + (s * 512 + b0 + b) * 768 + e0 + eq * 4);
    tile[b][eq * 4 + 0] = v.x; tile[b][eq * 4 + 1] = v.y;
    tile[b][eq * 4 + 2] = v.z; tile[b][eq * 4 + 3] = v.w;
  }
  __syncthreads();
  const int e = t & 63, bq = t >> 6;
  ushort_t tmp[16];
  #pragma unroll
  for (int i = 0; i < 16; ++i) tmp[i] = f2bf(tile[bq * 16 + i][e]);
  ushort_t* dst = Xt + (long)si * 393216 + (long)(e0 + e) * 512 + b0 + bq * 16;
  *(uint4*)(dst)     = *(uint4*)&tmp[0];
  *(uint4*)(dst + 8) = *(uint4*)&tmp[8];
}

// ---------------------------------------------------------------------------
extern "C" void kernel_launch(void* const* d_in, const int* in_sizes, int n_in,
                              void* d_out, int out_size, void* d_ws, size_t ws_size,
                              hipStream_t stream) {
  const float* X = (const float*)d_in[0];
  const float* R = (const float*)d_in[1];  // rotation_params
  const float* W = (const float*)d_in[2];  // entangle_params
  float* out = (float*)d_out;
  char* ws = (char*)d_ws;

  // ws: H hi/lo (768x768 each) | scores fp32 [SCI][512][512] | P bf16 | Xt bf16
  ushort_t* Hhi = (ushort_t*)ws;
  ushort_t* Hlo = Hhi + 768 * 768;
  const size_t hBytes = 2ull * 768 * 768 * 2;            // 2,359,296
  const size_t perS   = 262144ull * 4 + 262144ull * 2 + 393216ull * 2;  // 2,359,296
  long SCI = 1;
  if (ws_size > hBytes + perS) SCI = (long)((ws_size - hBytes) / perS);
  if (SCI < 1) SCI = 1;
  if (SCI > 512) SCI = 512;
  float*    scores = (float*)(ws + hBytes);
  ushort_t* Pm     = (ushort_t*)(ws + hBytes + (size_t)SCI * 1048576ull);
  ushort_t* Xt     = (ushort_t*)((char*)Pm + (size_t)SCI * 524288ull);

  // ---- K0: H = W * R^T  (768x768, bf16x3), split-stored hi/lo ----
  {
    MMP p{};
    p.Af = W;  p.aLd = 768; p.aZ = 0;
    p.Bf = R;  p.bLd = 768; p.bZ = 0;
    p.Chi = Hhi; p.Clo = Hlo; p.cLd = 768; p.zMode = 0;
    p.K = 768;
    mm<0, 0, 1, true><<<dim3(6, 6, 1), 256, 0, stream>>>(p);
  }
  // ---- K1: Z = X * H^T  (262144x768, bf16x3) -> d_out as per-s hi/lo planes ----
  {
    MMP p{};
    p.Af = X; p.aLd = 768; p.aZ = 0;
    p.Bhi = Hhi; p.Blo = Hlo; p.bLd = 768; p.bZ = 0;
    p.Chi = (ushort_t*)d_out; p.Clo = (ushort_t*)d_out + 393216; p.zMode = 1;
    p.K = 768;
    mm<0, 1, 1, true><<<dim3(6, 2048, 1), 256, 0, stream>>>(p);
  }

  for (long s0 = 0; s0 < 512; s0 += SCI) {
    int cur = (int)((512 - s0 < SCI) ? (512 - s0) : SCI);
    // ---- K2: scores_s = scale * Z_s * X_s^T  (bf16x3) ----
    {
      MMP p{};
      p.Ahi = (const ushort_t*)d_out + s0 * 786432;
      p.Alo = p.Ahi + 393216;
      p.aLd = 768; p.aZ = 786432;
      p.Bf = X + s0 * 393216; p.bLd = 768; p.bZ = 393216;
      p.Cf = scores; p.cLd = 512; p.cZ = 262144; p.cScale = SCALE;
      p.K = 768;
      mm<1, 0, 0, true><<<dim3(4, 4, cur), 256, 0, stream>>>(p);
    }
    // ---- K3: row softmax -> P bf16 ----
    softmax_rows<<<dim3(128, cur), 256, 0, stream>>>(scores, Pm);
    // ---- KT: Xt[si] = bf16(X_s^T) ----
    transpose_split<<<dim3(8, 12, cur), 256, 0, stream>>>(X, Xt, (int)s0);
    // ---- K4: out_s = P * V  (single bf16), overwrites Z_s in d_out ----
    {
      MMP p{};
      p.Ahi = Pm; p.aLd = 512; p.aZ = 262144;
      p.Bhi = Xt; p.bLd = 512; p.bZ = 393216;
      p.Cf = out + s0 * 393216; p.cLd = 768; p.cZ = 393216; p.cScale = 1.0f;
      p.K = 512;
      mm<2, 2, 0, false><<<dim3(6, 4, cur), 256, 0, stream>>>(p);
    }
  }
}